// Round 4
// baseline (5595.728 us; speedup 1.0000x reference)
//
#include <hip/hip_runtime.h>

typedef unsigned short ushort;
typedef unsigned int uint;
typedef __bf16 bf16x8 __attribute__((ext_vector_type(8)));
typedef ushort ushort8 __attribute__((ext_vector_type(8)));
typedef float f32x4 __attribute__((ext_vector_type(4)));

#define Z4 f32x4{0.f, 0.f, 0.f, 0.f}

__device__ __forceinline__ f32x4 mfma16(bf16x8 a, bf16x8 b, f32x4 c) {
    return __builtin_amdgcn_mfma_f32_16x16x32_bf16(a, b, c, 0, 0, 0);
}
__device__ __forceinline__ float bf2f(ushort h) {
    union { uint u; float f; } v; v.u = ((uint)h) << 16; return v.f;
}
__device__ __forceinline__ ushort f2bf(float f) {  // RNE
    union { float f; uint u; } v; v.f = f;
    uint u = v.u;
    uint r = (u + 0x7fffu + ((u >> 16) & 1u)) >> 16;
    return (ushort)r;
}
__device__ __forceinline__ float sigmoidf_(float x) { return 1.f / (1.f + __expf(-x)); }
__device__ __forceinline__ float tanhf_(float x) {
    float e = __expf(2.f * x);
    return 1.f - 2.f / (e + 1.f);
}

typedef __attribute__((address_space(1))) uint guint;
typedef __attribute__((address_space(3))) uint luint;
__device__ __forceinline__ void dma16(const ushort* g, ushort* l) {
    __builtin_amdgcn_global_load_lds((const guint*)g, (luint*)l, 16, 0, 0);
}
template <int N> __device__ __forceinline__ void ring_wait() {
    asm volatile("s_waitcnt vmcnt(%0)" ::"n"(N) : "memory");
}
// raw barrier: LDS ordering only — does NOT drain the per-wave DMA ring (vmcnt)
__device__ __forceinline__ void wg_sync() {
    asm volatile("s_waitcnt lgkmcnt(0)\n\ts_barrier" ::: "memory");
}

// ---------------------------------------------------------------------------
// Weight pre-pack, MFMA-B fragment-major: frag F = ntile*(K/32)+kf, 1 KB each.
// ---------------------------------------------------------------------------
__global__ void pack_direct_k(const float* __restrict__ src, ushort* __restrict__ dst,
                              int N, int K) {  // src row-major [N,K]
    int total = (N >> 4) * (K >> 5) * 64;
    int idx = blockIdx.x * 256 + threadIdx.x;
    if (idx >= total) return;
    int l = idx & 63, f = idx >> 6;
    int kfrags = K >> 5;
    int nt = f / kfrags, kf = f - nt * kfrags;
    int n = nt * 16 + (l & 15);
    int k0 = kf * 32 + (l >> 4) * 8;
    const float* s = src + (size_t)n * K + k0;
    ushort8 u;
#pragma unroll
    for (int j = 0; j < 8; j++) u[j] = f2bf(s[j]);
    *(ushort8*)&dst[(size_t)f * 512 + l * 8] = u;
}
__global__ void pack_trans_k(const float* __restrict__ src, ushort* __restrict__ dst,
                             int N, int K) {  // src row-major [K,N]
    int total = (N >> 4) * (K >> 5) * 64;
    int idx = blockIdx.x * 256 + threadIdx.x;
    if (idx >= total) return;
    int l = idx & 63, f = idx >> 6;
    int kfrags = K >> 5;
    int nt = f / kfrags, kf = f - nt * kfrags;
    int n = nt * 16 + (l & 15);
    int k0 = kf * 32 + (l >> 4) * 8;
    ushort8 u;
#pragma unroll
    for (int j = 0; j < 8; j++) u[j] = f2bf(src[(size_t)(k0 + j) * N + n]);
    *(ushort8*)&dst[(size_t)f * 512 + l * 8] = u;
}

// ---------------------------------------------------------------------------
// Fused MLP: X2 = relu(H@W1+b1)@W2+b2  -> bf16 [65536,256]
// ---------------------------------------------------------------------------
__global__ __launch_bounds__(256) void mlp_kernel(
    const float* __restrict__ H,     // [65536,128] fp32
    const ushort* __restrict__ W1P,  // packed N=512,K=128
    const float* __restrict__ b1,
    const ushort* __restrict__ W2P,  // packed N=256,K=512
    const float* __restrict__ b2,
    ushort* __restrict__ X2)         // [65536,256] bf16
{
    __shared__ __align__(16) ushort sH[64][136];
    __shared__ __align__(16) ushort sT[64][264];
    __shared__ float sb1[512], sb2[256];
    const int tid = threadIdx.x;
    const int w = tid >> 6, lane = tid & 63;
    const int q = lane >> 4, tc = lane & 15;
    const int lo8 = lane * 8;
    const int m0 = blockIdx.x * 64;

    {   // stage H 64x128 fp32 -> bf16
        int r = tid >> 2, c0 = (tid & 3) * 32;
        const float* src = H + (size_t)(m0 + r) * 128 + c0;
#pragma unroll
        for (int v = 0; v < 4; v++) {
            float4 a = *(const float4*)(src + v * 8);
            float4 b = *(const float4*)(src + v * 8 + 4);
            ushort8 u;
            u[0] = f2bf(a.x); u[1] = f2bf(a.y); u[2] = f2bf(a.z); u[3] = f2bf(a.w);
            u[4] = f2bf(b.x); u[5] = f2bf(b.y); u[6] = f2bf(b.z); u[7] = f2bf(b.w);
            *(ushort8*)&sH[r][c0 + v * 8] = u;
        }
    }
    for (int i = tid; i < 512; i += 256) sb1[i] = b1[i];
    if (tid < 256) sb2[tid] = b2[tid];
    __syncthreads();

    bf16x8 af[4];
#pragma unroll
    for (int kb = 0; kb < 4; kb++) af[kb] = *(const bf16x8*)&sH[w * 16 + tc][kb * 32 + q * 8];

    f32x4 accH[16];
#pragma unroll
    for (int nt = 0; nt < 16; nt++) accH[nt] = Z4;

#pragma unroll 1
    for (int half = 0; half < 2; half++) {
        __syncthreads();  // protect sT reuse across halves
#pragma unroll
        for (int j = 0; j < 16; j++) {
            int n = half * 256 + j * 16 + tc;
            const ushort* bp = W1P + (size_t)((half * 16 + j) * 4) * 512 + lo8;
            f32x4 a = Z4;
#pragma unroll
            for (int kb = 0; kb < 4; kb++)
                a = mfma16(af[kb], *(const bf16x8*)(bp + kb * 512), a);
            float bv = sb1[n];
#pragma unroll
            for (int i = 0; i < 4; i++)
                sT[w * 16 + q * 4 + i][j * 16 + tc] = f2bf(fmaxf(a[i] + bv, 0.f));
        }
        __syncthreads();

        bf16x8 a2[8];
#pragma unroll
        for (int kb = 0; kb < 8; kb++) a2[kb] = *(const bf16x8*)&sT[w * 16 + tc][kb * 32 + q * 8];
#pragma unroll
        for (int nt = 0; nt < 16; nt++) {
            const ushort* bp = W2P + (size_t)(nt * 16 + half * 8) * 512 + lo8;
#pragma unroll
            for (int kb = 0; kb < 8; kb++)
                accH[nt] = mfma16(a2[kb], *(const bf16x8*)(bp + kb * 512), accH[nt]);
        }
    }

#pragma unroll
    for (int nt = 0; nt < 16; nt++) {
        int col = nt * 16 + tc;
        float bv = sb2[col];
#pragma unroll
        for (int i = 0; i < 4; i++)
            X2[(size_t)(m0 + w * 16 + q * 4 + i) * 256 + col] = f2bf(accH[nt][i] + bv);
    }
}

// ---------------------------------------------------------------------------
// GEMM, packed-B: C = A @ B^T + bias.  A bf16 row-major [M,K], BP packed.
// mode 0: bf16 row-major out; 1: fp32 row-major out; 2: bf16 Xg-swizzle out
// ---------------------------------------------------------------------------
__global__ __launch_bounds__(256) void gemm128P(
    const ushort* __restrict__ A, const ushort* __restrict__ BP,
    const float* __restrict__ bias, void* __restrict__ Cout,
    int M, int N, int K, int mode)
{
    __shared__ __align__(16) ushort sA[128][40];
    const int tid = threadIdx.x;
    const int lane = tid & 63, wid = tid >> 6;
    const int q = lane >> 4, tc = lane & 15;
    const int lo8 = lane * 8;
    const int wm = (wid >> 1) * 64, wn = (wid & 1) * 64;
    const int bm = blockIdx.y * 128, bn = blockIdx.x * 128;

    f32x4 acc[4][4];
#pragma unroll
    for (int im = 0; im < 4; im++)
#pragma unroll
        for (int in_ = 0; in_ < 4; in_++) acc[im][in_] = Z4;

    const int arow = tid >> 1, acol = (tid & 1) * 16;
    const int kfrags = K >> 5;

    for (int kc = 0; kc < K; kc += 32) {
        const ushort* ga = A + (size_t)(bm + arow) * K + kc + acol;
        ushort8 va0 = *(const ushort8*)ga;
        ushort8 va1 = *(const ushort8*)(ga + 8);
        __syncthreads();
        *(ushort8*)&sA[arow][acol] = va0;
        *(ushort8*)&sA[arow][acol + 8] = va1;
        __syncthreads();

        bf16x8 af[4], bf[4];
#pragma unroll
        for (int im = 0; im < 4; im++) af[im] = *(const bf16x8*)&sA[wm + im * 16 + tc][q * 8];
#pragma unroll
        for (int in_ = 0; in_ < 4; in_++) {
            int nt = ((bn + wn) >> 4) + in_;
            bf[in_] = *(const bf16x8*)(BP + (size_t)(nt * kfrags + (kc >> 5)) * 512 + lo8);
        }
#pragma unroll
        for (int im = 0; im < 4; im++)
#pragma unroll
            for (int in_ = 0; in_ < 4; in_++)
                acc[im][in_] = mfma16(af[im], bf[in_], acc[im][in_]);
    }

#pragma unroll
    for (int in_ = 0; in_ < 4; in_++) {
        int col = bn + wn + in_ * 16 + tc;
        float bv = bias[col];
#pragma unroll
        for (int im = 0; im < 4; im++) {
            int row0 = bm + wm + im * 16 + q * 4;
#pragma unroll
            for (int r = 0; r < 4; r++) {
                float v = acc[im][in_][r] + bv;
                int row = row0 + r;
                if (mode == 0) {
                    ((ushort*)Cout)[(size_t)row * N + col] = f2bf(v);
                } else if (mode == 1) {
                    ((float*)Cout)[(size_t)row * N + col] = v;
                } else {
                    int b = row >> 7, t = row & 127;
                    size_t dst = (((size_t)(b >> 4) * 128 + t) * N + col) * 16 + (b & 15);
                    ((ushort*)Cout)[dst] = f2bf(v);
                }
            }
        }
    }
}

// ---------------------------------------------------------------------------
// Sequential scan, v4 (resubmit — round 3 was an infra failure, no data):
// TWO independent 16-row streams per WG (32 batch rows, 16 WGs).  Same
// barrier/phase structure and DMA cadence as v1 (the proven best), but each
// phase's fixed cost (barrier sync, LDS round-trip latency, DMA waits) is
// amortized over 2x the batch rows, and the weight stream (shared by both
// streams) halves per batch row.
//   - wOr/wOz persistent (128 regs -> AGPRs, as in v1).  Ohh re-streamed
//     4x/step like v1 (that cadence measured fastest).
//   - ring[8][2][2048] (64 KB): 4 KB chunks, 28/step, pump c+2 per chunk,
//     ring_wait<4> steady / <0> at the last chunk.  Per-chunk compute is 2x
//     v1 -> prefetch distance in TIME matches v1's 3-slot ring.
//   - chunk content is half-major; per-accumulator kf order is 0..7
//     everywhere -> bit-identical output vs v1.
//   - x-gates + biases in LDS (VGPR budget: keep VGPR+AGPR <= 256, the v3
//     spill lesson).
// Per-step per-wave vmcnt order: store(2) | xg(6) | O0,O1(8) | per-chunk
// pumps.  First consumer wait<4> drains store+xg+O0.
// ---------------------------------------------------------------------------
__global__ __launch_bounds__(512, 2) void scan_fused(
    const ushort* __restrict__ XgSw,  // [32][128][768][16] bf16 swizzled
    const ushort* __restrict__ OhrP, const ushort* __restrict__ OhzP,
    const ushort* __restrict__ OhhP,  // packed N=256,K=256
    const ushort* __restrict__ WhhP,  // packed N=768,K=256
    const float*  __restrict__ bhh,   // [768]
    ushort* __restrict__ hseq)        // [65536,256] bf16, row = b*128+t
{
    const int bx = blockIdx.x;  // 16 WGs x 32 batch rows
    const int tid = threadIdx.x;
    const int w = tid >> 6, lane = tid & 63;
    const int q = lane >> 4, tc = lane & 15;
    const int lo8 = lane * 8;

    __shared__ __align__(16) ushort ring[8][2][2048];   // 64 KB, per-wave
    __shared__ __align__(16) ushort xgL[2][3][4096];    // 48 KB, per-wave 512
    __shared__ __align__(16) ushort h_bf[2][16][264];   // 16.5 KB
    __shared__ __align__(16) ushort rh_bf[2][16][264];  // 16.5 KB
    __shared__ float sbhh[768];                         // 3 KB

    for (int i = tid; i < 2 * 16 * 264; i += 512) (&h_bf[0][0][0])[i] = 0;
    for (int i = tid; i < 768; i += 512) sbhh[i] = bhh[i];

    const int colbase = w * 32 + tc;

    // persistent ODE r/z weights (128 regs -> AGPR file, v1-proven)
    bf16x8 wOr[16], wOz[16];
#pragma unroll
    for (int f = 0; f < 16; f++) {
        wOr[f] = *(const bf16x8*)(OhrP + (size_t)(w * 16 + f) * 512 + lo8);
        wOz[f] = *(const bf16x8*)(OhzP + (size_t)(w * 16 + f) * 512 + lo8);
    }

    float hrA[2][4] = {{0.f,0.f,0.f,0.f},{0.f,0.f,0.f,0.f}};
    float hrB[2][4] = {{0.f,0.f,0.f,0.f},{0.f,0.f,0.f,0.f}};

    auto pump4k = [&](const ushort* g, int slot) {
        asm volatile("s_waitcnt lgkmcnt(0)" ::: "memory");
        g += lo8;
        ushort* sb = &ring[w][slot][0];
        dma16(g, sb); dma16(g + 512, sb + 512);
        dma16(g + 1024, sb + 1024); dma16(g + 1536, sb + 1536);
    };
    // Ohh chunk cc (0..3): content nt=cc&1, kf-half=cc>>1; slot=cc&1
    auto pumpO = [&](int cc) {
        pump4k(OhhP + (size_t)(w * 16 + (cc & 1) * 8 + (cc >> 1) * 4) * 512, cc & 1);
    };
    // Whh chunk j (0..11): half=j/6, b=j%6 (nt=b/3, gate=b%3); slot=j&1
    auto pumpW = [&](int j) {
        int half = j / 6, b = j - half * 6;
        int nt = b / 3, gg = b - nt * 3;
        pump4k(WhhP + (size_t)((gg * 16 + w * 2 + nt) * 8 + half * 4) * 512, j & 1);
    };
    // x-gates for both streams: 6 x 1 KB DMA (stream s, gate g)
    auto pumpXG = [&](int tt) {
        asm volatile("s_waitcnt lgkmcnt(0)" ::: "memory");
#pragma unroll
        for (int s2 = 0; s2 < 2; s2++)
#pragma unroll
            for (int g = 0; g < 3; g++) {
                const ushort* src = XgSw +
                    (((size_t)(2 * bx + s2) * 128 + tt) * 768 + g * 256 + w * 32) * 16 + lo8;
                dma16(src, &xgL[s2][g][w * 512]);
            }
    };

    __syncthreads();  // zero-fill + sbhh visible (no DMA yet)

    pumpXG(0);
    pumpO(0); pumpO(1);

#pragma unroll 1
    for (int t = 0; t < 128; t++) {
        // ---- 4 Euler ODE substeps ----
#pragma unroll 1
        for (int s = 0; s < 4; s++) {
            // R/Z MFMA (register weights), kh-split fragment loads
            f32x4 arA[2] = {Z4, Z4}, azA[2] = {Z4, Z4};
            f32x4 arB[2] = {Z4, Z4}, azB[2] = {Z4, Z4};
#pragma unroll
            for (int kh = 0; kh < 2; kh++) {
                bf16x8 afA[4], afB[4];
#pragma unroll
                for (int k = 0; k < 4; k++) {
                    afA[k] = *(const bf16x8*)&h_bf[0][tc][(kh * 4 + k) * 32 + q * 8];
                    afB[k] = *(const bf16x8*)&h_bf[1][tc][(kh * 4 + k) * 32 + q * 8];
                }
#pragma unroll
                for (int nt = 0; nt < 2; nt++)
#pragma unroll
                    for (int k = 0; k < 4; k++) {
                        arA[nt] = mfma16(afA[k], wOr[nt * 8 + kh * 4 + k], arA[nt]);
                        azA[nt] = mfma16(afA[k], wOz[nt * 8 + kh * 4 + k], azA[nt]);
                        arB[nt] = mfma16(afB[k], wOr[nt * 8 + kh * 4 + k], arB[nt]);
                        azB[nt] = mfma16(afB[k], wOz[nt * 8 + kh * 4 + k], azB[nt]);
                    }
            }
#pragma unroll
            for (int nt = 0; nt < 2; nt++)
#pragma unroll
                for (int i = 0; i < 4; i++) {
                    rh_bf[0][q * 4 + i][colbase + nt * 16] =
                        f2bf(sigmoidf_(arA[nt][i]) * hrA[nt][i]);
                    rh_bf[1][q * 4 + i][colbase + nt * 16] =
                        f2bf(sigmoidf_(arB[nt][i]) * hrB[nt][i]);
                }
            wg_sync();  // rh ready

            // U phase: 4 ring chunks (half-major), both streams per chunk
            f32x4 uuA[2] = {Z4, Z4}, uuB[2] = {Z4, Z4};
            bf16x8 auA[4], auB[4];
#pragma unroll
            for (int cc = 0; cc < 4; cc++) {
                if ((cc & 1) == 0) {  // (re)load au half cc>>1
                    const int kh = cc >> 1;
                    auA[0] = *(const bf16x8*)&rh_bf[0][tc][(kh * 4 + 0) * 32 + q * 8];
                    auA[1] = *(const bf16x8*)&rh_bf[0][tc][(kh * 4 + 1) * 32 + q * 8];
                    auA[2] = *(const bf16x8*)&rh_bf[0][tc][(kh * 4 + 2) * 32 + q * 8];
                    auA[3] = *(const bf16x8*)&rh_bf[0][tc][(kh * 4 + 3) * 32 + q * 8];
                    auB[0] = *(const bf16x8*)&rh_bf[1][tc][(kh * 4 + 0) * 32 + q * 8];
                    auB[1] = *(const bf16x8*)&rh_bf[1][tc][(kh * 4 + 1) * 32 + q * 8];
                    auB[2] = *(const bf16x8*)&rh_bf[1][tc][(kh * 4 + 2) * 32 + q * 8];
                    auB[3] = *(const bf16x8*)&rh_bf[1][tc][(kh * 4 + 3) * 32 + q * 8];
                }
                ring_wait<4>();
                const ushort* sb = &ring[w][cc & 1][0] + lo8;
                bf16x8 v0 = *(const bf16x8*)(sb);
                bf16x8 v1 = *(const bf16x8*)(sb + 512);
                bf16x8 v2 = *(const bf16x8*)(sb + 1024);
                bf16x8 v3 = *(const bf16x8*)(sb + 1536);
                {
                    int c2 = s * 4 + cc + 2;  // next-next global chunk
                    if (c2 < 16) pumpO(c2 & 3); else pumpW(c2 - 16);
                }
                const int nt = cc & 1;
                uuA[nt] = mfma16(auA[0], v0, uuA[nt]);
                uuA[nt] = mfma16(auA[1], v1, uuA[nt]);
                uuA[nt] = mfma16(auA[2], v2, uuA[nt]);
                uuA[nt] = mfma16(auA[3], v3, uuA[nt]);
                uuB[nt] = mfma16(auB[0], v0, uuB[nt]);
                uuB[nt] = mfma16(auB[1], v1, uuB[nt]);
                uuB[nt] = mfma16(auB[2], v2, uuB[nt]);
                uuB[nt] = mfma16(auB[3], v3, uuB[nt]);
            }
#pragma unroll
            for (int nt = 0; nt < 2; nt++)
#pragma unroll
                for (int i = 0; i < 4; i++) {
                    float zA = sigmoidf_(azA[nt][i]);
                    float hA = hrA[nt][i];
                    float hnA = hA + 0.25f * (1.f - zA) * (tanhf_(uuA[nt][i]) - hA);
                    hrA[nt][i] = hnA;
                    h_bf[0][q * 4 + i][colbase + nt * 16] = f2bf(hnA);
                    float zB = sigmoidf_(azB[nt][i]);
                    float hB = hrB[nt][i];
                    float hnB = hB + 0.25f * (1.f - zB) * (tanhf_(uuB[nt][i]) - hB);
                    hrB[nt][i] = hnB;
                    h_bf[1][q * 4 + i][colbase + nt * 16] = f2bf(hnB);
                }
            wg_sync();  // h ready
        }

        // ---- GRU h-part: Whh, 12 chunks (half-major), both streams ----
        f32x4 accrA[2] = {Z4, Z4}, acczA[2] = {Z4, Z4}, accnA[2] = {Z4, Z4};
        f32x4 accrB[2] = {Z4, Z4}, acczB[2] = {Z4, Z4}, accnB[2] = {Z4, Z4};
        bf16x8 ahA[4], ahB[4];
#define GRU_CHUNK(J, WN)                                                       \
        {                                                                      \
            constexpr int half_ = (J) / 6, b_ = (J) - half_ * 6;               \
            constexpr int nt_ = b_ / 3, gg_ = b_ - nt_ * 3;                    \
            if ((J) == 0 || (J) == 6) {                                        \
                ahA[0] = *(const bf16x8*)&h_bf[0][tc][(half_ * 4 + 0) * 32 + q * 8]; \
                ahA[1] = *(const bf16x8*)&h_bf[0][tc][(half_ * 4 + 1) * 32 + q * 8]; \
                ahA[2] = *(const bf16x8*)&h_bf[0][tc][(half_ * 4 + 2) * 32 + q * 8]; \
                ahA[3] = *(const bf16x8*)&h_bf[0][tc][(half_ * 4 + 3) * 32 + q * 8]; \
                ahB[0] = *(const bf16x8*)&h_bf[1][tc][(half_ * 4 + 0) * 32 + q * 8]; \
                ahB[1] = *(const bf16x8*)&h_bf[1][tc][(half_ * 4 + 1) * 32 + q * 8]; \
                ahB[2] = *(const bf16x8*)&h_bf[1][tc][(half_ * 4 + 2) * 32 + q * 8]; \
                ahB[3] = *(const bf16x8*)&h_bf[1][tc][(half_ * 4 + 3) * 32 + q * 8]; \
            }                                                                  \
            ring_wait<WN>();                                                   \
            const ushort* sb = &ring[w][(J) & 1][0] + lo8;                     \
            bf16x8 v0 = *(const bf16x8*)(sb);                                  \
            bf16x8 v1 = *(const bf16x8*)(sb + 512);                            \
            bf16x8 v2 = *(const bf16x8*)(sb + 1024);                           \
            bf16x8 v3 = *(const bf16x8*)(sb + 1536);                           \
            if ((J) <= 9) pumpW((J) + 2);                                      \
            f32x4* tA = (gg_ == 0) ? &accrA[nt_] : (gg_ == 1) ? &acczA[nt_]    \
                                                              : &accnA[nt_];  \
            f32x4* tB = (gg_ == 0) ? &accrB[nt_] : (gg_ == 1) ? &acczB[nt_]   \
                                                              : &accnB[nt_];  \
            *tA = mfma16(ahA[0], v0, *tA);                                     \
            *tA = mfma16(ahA[1], v1, *tA);                                     \
            *tA = mfma16(ahA[2], v2, *tA);                                     \
            *tA = mfma16(ahA[3], v3, *tA);                                     \
            *tB = mfma16(ahB[0], v0, *tB);                                     \
            *tB = mfma16(ahB[1], v1, *tB);                                     \
            *tB = mfma16(ahB[2], v2, *tB);                                     \
            *tB = mfma16(ahB[3], v3, *tB);                                     \
        }
        GRU_CHUNK(0, 4)  GRU_CHUNK(1, 4)  GRU_CHUNK(2, 4)  GRU_CHUNK(3, 4)
        GRU_CHUNK(4, 4)  GRU_CHUNK(5, 4)  GRU_CHUNK(6, 4)  GRU_CHUNK(7, 4)
        GRU_CHUNK(8, 4)  GRU_CHUNK(9, 4)  GRU_CHUNK(10, 4) GRU_CHUNK(11, 0)
#undef GRU_CHUNK
        wg_sync();  // all h_bf reads done

        // ---- GRU epilogue (xg DMA long drained; biases from LDS) ----
#pragma unroll
        for (int nt = 0; nt < 2; nt++) {
            int col = colbase + nt * 16;
            float rb = sbhh[col], zb = sbhh[256 + col], hb = sbhh[512 + col];
            int xoff = w * 512 + (tc + nt * 16) * 16 + q * 4;
            uint2 urA = *(const uint2*)&xgL[0][0][xoff];
            uint2 uzA = *(const uint2*)&xgL[0][1][xoff];
            uint2 unA = *(const uint2*)&xgL[0][2][xoff];
            uint2 urB = *(const uint2*)&xgL[1][0][xoff];
            uint2 uzB = *(const uint2*)&xgL[1][1][xoff];
            uint2 unB = *(const uint2*)&xgL[1][2][xoff];
#pragma unroll
            for (int i = 0; i < 4; i++) {
                int sh = (i & 1) * 16;
                uint wrA = (i < 2) ? urA.x : urA.y, wzA = (i < 2) ? uzA.x : uzA.y,
                     wnA = (i < 2) ? unA.x : unA.y;
                float rgA = sigmoidf_(accrA[nt][i] + bf2f((ushort)(wrA >> sh)) + rb);
                float zgA = sigmoidf_(acczA[nt][i] + bf2f((ushort)(wzA >> sh)) + zb);
                float ngA = tanhf_(bf2f((ushort)(wnA >> sh)) + rgA * (accnA[nt][i] + hb));
                float hnA = (1.f - zgA) * ngA + zgA * hrA[nt][i];
                hrA[nt][i] = hnA;
                h_bf[0][q * 4 + i][col] = f2bf(hnA);
                uint wrB = (i < 2) ? urB.x : urB.y, wzB = (i < 2) ? uzB.x : uzB.y,
                     wnB = (i < 2) ? unB.x : unB.y;
                float rgB = sigmoidf_(accrB[nt][i] + bf2f((ushort)(wrB >> sh)) + rb);
                float zgB = sigmoidf_(acczB[nt][i] + bf2f((ushort)(wzB >> sh)) + zb);
                float ngB = tanhf_(bf2f((ushort)(wnB >> sh)) + rgB * (accnB[nt][i] + hb));
                float hnB = (1.f - zgB) * ngB + zgB * hrB[nt][i];
                hrB[nt][i] = hnB;
                h_bf[1][q * 4 + i][col] = f2bf(hnB);
            }
        }
        wg_sync();  // h_new visible

        // ---- coalesced h stores + next step's prefetch (store,xg,O0,O1) ----
        {
            int row = tid >> 5, col = (tid & 31) * 8;
            ushort8 hv0 = *(const ushort8*)&h_bf[0][row][col];
            *(ushort8*)&hseq[((size_t)(bx * 32 + row) * 128 + t) * 256 + col] = hv0;
            ushort8 hv1 = *(const ushort8*)&h_bf[1][row][col];
            *(ushort8*)&hseq[((size_t)(bx * 32 + 16 + row) * 128 + t) * 256 + col] = hv1;
        }
        if (t < 127) {
            pumpXG(t + 1);
            pumpO(0); pumpO(1);
        }
    }
}

// ---------------------------------------------------------------------------
// Launch.  Workspace 129.6 MB:
//   [0, 100663296)            Xg swizzled [32][128][768][16] bf16
//   [100663296, 134217728)    X2 [65536,256] bf16  (aliased by hseq after use)
//   [134217728, ...)          packed weights (1.44 MB)
// ---------------------------------------------------------------------------
extern "C" void kernel_launch(void* const* d_in, const int* in_sizes, int n_in,
                              void* d_out, int out_size, void* d_ws, size_t ws_size,
                              hipStream_t stream) {
    const float* H   = (const float*)d_in[0];
    const float* W1  = (const float*)d_in[2];
    const float* b1  = (const float*)d_in[3];
    const float* W2  = (const float*)d_in[4];
    const float* b2  = (const float*)d_in[5];
    const float* Ohr = (const float*)d_in[6];
    const float* Ohz = (const float*)d_in[7];
    const float* Ohh = (const float*)d_in[8];
    const float* Wih = (const float*)d_in[9];
    const float* Whh = (const float*)d_in[10];
    const float* bih = (const float*)d_in[11];
    const float* bhh = (const float*)d_in[12];
    const float* Wr  = (const float*)d_in[13];
    const float* br  = (const float*)d_in[14];
    float* out = (float*)d_out;
    char* ws = (char*)d_ws;

    ushort* Xg   = (ushort*)(ws);
    ushort* X2   = (ushort*)(ws + 100663296);
    ushort* hseq = X2;  // alias: X2 dead before scan writes hseq
    char* pk = ws + 134217728;
    ushort* W1P  = (ushort*)(pk);
    ushort* W2P  = (ushort*)(pk + 131072);
    ushort* WrP  = (ushort*)(pk + 393216);
    ushort* OhrP = (ushort*)(pk + 458752);
    ushort* OhzP = (ushort*)(pk + 589824);
    ushort* OhhP = (ushort*)(pk + 720896);
    ushort* WihP = (ushort*)(pk + 851968);
    // end at +1245184

    pack_trans_k<<<dim3(32),  256, 0, stream>>>(W1,  W1P, 512, 128);
    pack_trans_k<<<dim3(64),  256, 0, stream>>>(W2,  W2P, 256, 512);
    pack_trans_k<<<dim3(16),  256, 0, stream>>>(Wr,  WrP, 128, 256);
    pack_direct_k<<<dim3(32), 256, 0, stream>>>(Ohr, OhrP, 256, 256);
    pack_direct_k<<<dim3(32), 256, 0, stream>>>(Ohz, OhzP, 256, 256);
    pack_direct_k<<<dim3(32), 256, 0, stream>>>(Ohh, OhhP, 256, 256);
    pack_direct_k<<<dim3(96), 256, 0, stream>>>(Wih, WihP, 768, 256);
    pack_direct_k<<<dim3(96), 256, 0, stream>>>(Whh, (ushort*)(pk + 1245184), 768, 256);
    ushort* WhhP = (ushort*)(pk + 1245184);

    // Phase A: X2 = MLP(H); Xg = X2 @ Wih^T + bih (swizzled for the scan)
    mlp_kernel<<<dim3(1024), 256, 0, stream>>>(H, W1P, b1, W2P, b2, X2);
    gemm128P<<<dim3(6, 512), 256, 0, stream>>>(X2, WihP, bih, Xg, 65536, 768, 256, 2);

    // Phase B: sequential scan -> hseq (16 WGs x 32 batch rows, 2 streams)
    scan_fused<<<dim3(16), 512, 0, stream>>>(Xg, OhrP, OhzP, OhhP, WhhP, bhh, hseq);

    // Phase C: out = hseq @ Wr + br (fp32)
    gemm128P<<<dim3(1, 512), 256, 0, stream>>>(hseq, WrP, br, out, 65536, 128, 256, 1);
}

// Round 5
// 2772.403 us; speedup vs baseline: 2.0184x; 2.0184x over previous
//
#include <hip/hip_runtime.h>

typedef unsigned short ushort;
typedef unsigned int uint;
typedef __bf16 bf16x8 __attribute__((ext_vector_type(8)));
typedef ushort ushort8 __attribute__((ext_vector_type(8)));
typedef float f32x4 __attribute__((ext_vector_type(4)));

#define Z4 f32x4{0.f, 0.f, 0.f, 0.f}

__device__ __forceinline__ f32x4 mfma16(bf16x8 a, bf16x8 b, f32x4 c) {
    return __builtin_amdgcn_mfma_f32_16x16x32_bf16(a, b, c, 0, 0, 0);
}
__device__ __forceinline__ float bf2f(ushort h) {
    union { uint u; float f; } v; v.u = ((uint)h) << 16; return v.f;
}
__device__ __forceinline__ ushort f2bf(float f) {  // RNE
    union { float f; uint u; } v; v.f = f;
    uint u = v.u;
    uint r = (u + 0x7fffu + ((u >> 16) & 1u)) >> 16;
    return (ushort)r;
}
__device__ __forceinline__ float sigmoidf_(float x) { return 1.f / (1.f + __expf(-x)); }
__device__ __forceinline__ float tanhf_(float x) {
    float e = __expf(2.f * x);
    return 1.f - 2.f / (e + 1.f);
}

typedef __attribute__((address_space(1))) uint guint;
typedef __attribute__((address_space(3))) uint luint;
__device__ __forceinline__ void dma16(const ushort* g, ushort* l) {
    __builtin_amdgcn_global_load_lds((const guint*)g, (luint*)l, 16, 0, 0);
}
template <int N> __device__ __forceinline__ void ring_wait() {
    asm volatile("s_waitcnt vmcnt(%0)" ::"n"(N) : "memory");
}
// raw barrier: LDS ordering only — does NOT drain the per-wave DMA ring (vmcnt)
__device__ __forceinline__ void wg_sync() {
    asm volatile("s_waitcnt lgkmcnt(0)\n\ts_barrier" ::: "memory");
}

// ---------------------------------------------------------------------------
// Weight pre-pack, MFMA-B fragment-major: frag F = ntile*(K/32)+kf, 1 KB each.
// ---------------------------------------------------------------------------
__global__ void pack_direct_k(const float* __restrict__ src, ushort* __restrict__ dst,
                              int N, int K) {  // src row-major [N,K]
    int total = (N >> 4) * (K >> 5) * 64;
    int idx = blockIdx.x * 256 + threadIdx.x;
    if (idx >= total) return;
    int l = idx & 63, f = idx >> 6;
    int kfrags = K >> 5;
    int nt = f / kfrags, kf = f - nt * kfrags;
    int n = nt * 16 + (l & 15);
    int k0 = kf * 32 + (l >> 4) * 8;
    const float* s = src + (size_t)n * K + k0;
    ushort8 u;
#pragma unroll
    for (int j = 0; j < 8; j++) u[j] = f2bf(s[j]);
    *(ushort8*)&dst[(size_t)f * 512 + l * 8] = u;
}
__global__ void pack_trans_k(const float* __restrict__ src, ushort* __restrict__ dst,
                             int N, int K) {  // src row-major [K,N]
    int total = (N >> 4) * (K >> 5) * 64;
    int idx = blockIdx.x * 256 + threadIdx.x;
    if (idx >= total) return;
    int l = idx & 63, f = idx >> 6;
    int kfrags = K >> 5;
    int nt = f / kfrags, kf = f - nt * kfrags;
    int n = nt * 16 + (l & 15);
    int k0 = kf * 32 + (l >> 4) * 8;
    ushort8 u;
#pragma unroll
    for (int j = 0; j < 8; j++) u[j] = f2bf(src[(size_t)(k0 + j) * N + n]);
    *(ushort8*)&dst[(size_t)f * 512 + l * 8] = u;
}

// ---------------------------------------------------------------------------
// Fused MLP: X2 = relu(H@W1+b1)@W2+b2  -> bf16 [65536,256]
// ---------------------------------------------------------------------------
__global__ __launch_bounds__(256) void mlp_kernel(
    const float* __restrict__ H,     // [65536,128] fp32
    const ushort* __restrict__ W1P,  // packed N=512,K=128
    const float* __restrict__ b1,
    const ushort* __restrict__ W2P,  // packed N=256,K=512
    const float* __restrict__ b2,
    ushort* __restrict__ X2)         // [65536,256] bf16
{
    __shared__ __align__(16) ushort sH[64][136];
    __shared__ __align__(16) ushort sT[64][264];
    __shared__ float sb1[512], sb2[256];
    const int tid = threadIdx.x;
    const int w = tid >> 6, lane = tid & 63;
    const int q = lane >> 4, tc = lane & 15;
    const int lo8 = lane * 8;
    const int m0 = blockIdx.x * 64;

    {   // stage H 64x128 fp32 -> bf16
        int r = tid >> 2, c0 = (tid & 3) * 32;
        const float* src = H + (size_t)(m0 + r) * 128 + c0;
#pragma unroll
        for (int v = 0; v < 4; v++) {
            float4 a = *(const float4*)(src + v * 8);
            float4 b = *(const float4*)(src + v * 8 + 4);
            ushort8 u;
            u[0] = f2bf(a.x); u[1] = f2bf(a.y); u[2] = f2bf(a.z); u[3] = f2bf(a.w);
            u[4] = f2bf(b.x); u[5] = f2bf(b.y); u[6] = f2bf(b.z); u[7] = f2bf(b.w);
            *(ushort8*)&sH[r][c0 + v * 8] = u;
        }
    }
    for (int i = tid; i < 512; i += 256) sb1[i] = b1[i];
    if (tid < 256) sb2[tid] = b2[tid];
    __syncthreads();

    bf16x8 af[4];
#pragma unroll
    for (int kb = 0; kb < 4; kb++) af[kb] = *(const bf16x8*)&sH[w * 16 + tc][kb * 32 + q * 8];

    f32x4 accH[16];
#pragma unroll
    for (int nt = 0; nt < 16; nt++) accH[nt] = Z4;

#pragma unroll 1
    for (int half = 0; half < 2; half++) {
        __syncthreads();  // protect sT reuse across halves
#pragma unroll
        for (int j = 0; j < 16; j++) {
            int n = half * 256 + j * 16 + tc;
            const ushort* bp = W1P + (size_t)((half * 16 + j) * 4) * 512 + lo8;
            f32x4 a = Z4;
#pragma unroll
            for (int kb = 0; kb < 4; kb++)
                a = mfma16(af[kb], *(const bf16x8*)(bp + kb * 512), a);
            float bv = sb1[n];
#pragma unroll
            for (int i = 0; i < 4; i++)
                sT[w * 16 + q * 4 + i][j * 16 + tc] = f2bf(fmaxf(a[i] + bv, 0.f));
        }
        __syncthreads();

        bf16x8 a2[8];
#pragma unroll
        for (int kb = 0; kb < 8; kb++) a2[kb] = *(const bf16x8*)&sT[w * 16 + tc][kb * 32 + q * 8];
#pragma unroll
        for (int nt = 0; nt < 16; nt++) {
            const ushort* bp = W2P + (size_t)(nt * 16 + half * 8) * 512 + lo8;
#pragma unroll
            for (int kb = 0; kb < 8; kb++)
                accH[nt] = mfma16(a2[kb], *(const bf16x8*)(bp + kb * 512), accH[nt]);
        }
    }

#pragma unroll
    for (int nt = 0; nt < 16; nt++) {
        int col = nt * 16 + tc;
        float bv = sb2[col];
#pragma unroll
        for (int i = 0; i < 4; i++)
            X2[(size_t)(m0 + w * 16 + q * 4 + i) * 256 + col] = f2bf(accH[nt][i] + bv);
    }
}

// ---------------------------------------------------------------------------
// GEMM, packed-B: C = A @ B^T + bias.  A bf16 row-major [M,K], BP packed.
// mode 0: bf16 row-major out; 1: fp32 row-major out; 2: bf16 Xg-swizzle out
// ---------------------------------------------------------------------------
__global__ __launch_bounds__(256) void gemm128P(
    const ushort* __restrict__ A, const ushort* __restrict__ BP,
    const float* __restrict__ bias, void* __restrict__ Cout,
    int M, int N, int K, int mode)
{
    __shared__ __align__(16) ushort sA[128][40];
    const int tid = threadIdx.x;
    const int lane = tid & 63, wid = tid >> 6;
    const int q = lane >> 4, tc = lane & 15;
    const int lo8 = lane * 8;
    const int wm = (wid >> 1) * 64, wn = (wid & 1) * 64;
    const int bm = blockIdx.y * 128, bn = blockIdx.x * 128;

    f32x4 acc[4][4];
#pragma unroll
    for (int im = 0; im < 4; im++)
#pragma unroll
        for (int in_ = 0; in_ < 4; in_++) acc[im][in_] = Z4;

    const int arow = tid >> 1, acol = (tid & 1) * 16;
    const int kfrags = K >> 5;

    for (int kc = 0; kc < K; kc += 32) {
        const ushort* ga = A + (size_t)(bm + arow) * K + kc + acol;
        ushort8 va0 = *(const ushort8*)ga;
        ushort8 va1 = *(const ushort8*)(ga + 8);
        __syncthreads();
        *(ushort8*)&sA[arow][acol] = va0;
        *(ushort8*)&sA[arow][acol + 8] = va1;
        __syncthreads();

        bf16x8 af[4], bf[4];
#pragma unroll
        for (int im = 0; im < 4; im++) af[im] = *(const bf16x8*)&sA[wm + im * 16 + tc][q * 8];
#pragma unroll
        for (int in_ = 0; in_ < 4; in_++) {
            int nt = ((bn + wn) >> 4) + in_;
            bf[in_] = *(const bf16x8*)(BP + (size_t)(nt * kfrags + (kc >> 5)) * 512 + lo8);
        }
#pragma unroll
        for (int im = 0; im < 4; im++)
#pragma unroll
            for (int in_ = 0; in_ < 4; in_++)
                acc[im][in_] = mfma16(af[im], bf[in_], acc[im][in_]);
    }

#pragma unroll
    for (int in_ = 0; in_ < 4; in_++) {
        int col = bn + wn + in_ * 16 + tc;
        float bv = bias[col];
#pragma unroll
        for (int im = 0; im < 4; im++) {
            int row0 = bm + wm + im * 16 + q * 4;
#pragma unroll
            for (int r = 0; r < 4; r++) {
                float v = acc[im][in_][r] + bv;
                int row = row0 + r;
                if (mode == 0) {
                    ((ushort*)Cout)[(size_t)row * N + col] = f2bf(v);
                } else if (mode == 1) {
                    ((float*)Cout)[(size_t)row * N + col] = v;
                } else {
                    int b = row >> 7, t = row & 127;
                    size_t dst = (((size_t)(b >> 4) * 128 + t) * N + col) * 16 + (b & 15);
                    ((ushort*)Cout)[dst] = f2bf(v);
                }
            }
        }
    }
}

// ---------------------------------------------------------------------------
// Sequential scan, v5: 16-WAVE WGs, half work per wave, 4 waves/SIMD.
// Round-4 evidence: scan time is LINEAR in per-wave serial work at fixed
// waves/SIMD (v4: 2x work -> exactly 2x time).  So: same 32 WGs x 16 rows,
// but 1024 threads = 16 waves; wave w owns ntile w (16 cols).  Per-wave
// MFMA/transcendental/f2bf work halves; 4 waves/SIMD doubles latency hiding.
//   - HARD CONSTRAINT: 16 waves/WG requires <=128 VGPR+AGPR/thread (else
//     unlaunchable).  Persistent wOr/wOz = 64 regs (AGPR file); all A-frags
//     loaded kh-split or per-chunk (<=16 live); xg in 3 uint2 regs; single-
//     ntile accumulators.  ~115 peak estimate.
//   - v1-proven 28-chunk/step cadence, 2 KB chunks (2 frags, 2x dma16/pump),
//     3-slot/wave ring (96 KB).  Chunks: 4 substeps x 4 (Ohh) + 12 (Whh,
//     kf-major across gates so 3 acc chains interleave; per-acc kf order
//     still 0..7 ascending -> bit-identical output).
//   - vmcnt ledger (per wave, per step): store(1) | xg(3) | 3 pumps(6),
//     then 1 pump per chunk-read through read 24.  First wait<4> leaves
//     pumps 1,2 in flight, drains chunk0+xg+store.  Steady <4>; GRU tail
//     J=10 -> <2>, J=11 -> <0> (2-load chunks).
// ---------------------------------------------------------------------------
__global__ __launch_bounds__(1024) void scan_fused(
    const ushort* __restrict__ XgSw,  // [32][128][768][16] bf16 swizzled
    const ushort* __restrict__ OhrP, const ushort* __restrict__ OhzP,
    const ushort* __restrict__ OhhP,  // packed N=256,K=256
    const ushort* __restrict__ WhhP,  // packed N=768,K=256
    const float*  __restrict__ bhh,   // [768]
    ushort* __restrict__ hseq)        // [65536,256] bf16, row = b*128+t
{
    const int bx = blockIdx.x;        // 32 WGs x 16 rows
    const int m0 = bx * 16;
    const int tid = threadIdx.x;
    const int w = tid >> 6, lane = tid & 63;   // 16 waves
    const int q = lane >> 4, tc = lane & 15;
    const int lo8 = lane * 8;
    const int colbase = w * 16 + tc;           // this wave's ntile = w

    __shared__ __align__(16) ushort ring[16][3][1024];  // 96 KB (2 KB/slot)
    __shared__ __align__(16) ushort h_bf[16][264];      // 8.25 KB
    __shared__ __align__(16) ushort rh_bf[16][264];     // 8.25 KB

    for (int i = tid; i < 16 * 264; i += 1024) (&h_bf[0][0])[i] = 0;

    // per-thread biases (1 ntile -> scalars)
    float rbv = bhh[colbase], zbv = bhh[256 + colbase], hnbv = bhh[512 + colbase];

    // persistent ODE r/z weights, this wave's ntile: 16 frags = 64 regs
    bf16x8 wOr[8], wOz[8];
#pragma unroll
    for (int f = 0; f < 8; f++) {
        wOr[f] = *(const bf16x8*)(OhrP + (size_t)(w * 8 + f) * 512 + lo8);
        wOz[f] = *(const bf16x8*)(OhzP + (size_t)(w * 8 + f) * 512 + lo8);
    }

    float hreg[4] = {0.f, 0.f, 0.f, 0.f};

    int ic = 0, islot = 0, slot = 0;
    // 2 KB pump: chunk ic of the step's fixed 28-chunk sequence.
    //   ic 0..15: Ohh substep chunks (4/substep), frags w*8 + (ic&3)*2 .. +1
    //   ic 16..27: Whh, j=ic-16: gate g=j%3, kc=j/3, frags (g*16+w)*8+kc*2..+1
    auto pump = [&]() {
        if (ic >= 28) return;
        asm volatile("s_waitcnt lgkmcnt(0)" ::: "memory");  // slot-reuse fence
        const ushort* g;
        if (ic < 16) {
            g = OhhP + (size_t)(w * 8 + (ic & 3) * 2) * 512;
        } else {
            int j = ic - 16, gg = j % 3, kc = j / 3;
            g = WhhP + (size_t)((gg * 16 + w) * 8 + kc * 2) * 512;
        }
        g += lo8;
        ushort* sb = &ring[w][islot][0];
        dma16(g, sb); dma16(g + 512, sb + 512);
        ic++; islot = (islot == 2) ? 0 : islot + 1;
    };

    __syncthreads();  // zero-fill visible (no DMA yet)

#pragma unroll 1
    for (int t = 0; t < 128; t++) {
        // x-gates for this thread's 4 outputs (3 vmem loads; drained by the
        // first ring_wait<4> of the step)
        const ushort* xgp = XgSw + (((size_t)bx * 128 + t) * 768) * 16;
        uint2 xg[3];
#pragma unroll
        for (int g = 0; g < 3; g++)
            xg[g] = *(const uint2*)(xgp + (size_t)(g * 256 + colbase) * 16 + q * 4);

        ic = 0; islot = 0; slot = 0;
        pump(); pump(); pump();

        // ---- 4 Euler ODE substeps ----
#pragma unroll 1
        for (int s = 0; s < 4; s++) {
            f32x4 ar = Z4, az = Z4;
#pragma unroll
            for (int kh = 0; kh < 2; kh++) {
                bf16x8 af[4];
#pragma unroll
                for (int k = 0; k < 4; k++)
                    af[k] = *(const bf16x8*)&h_bf[tc][(kh * 4 + k) * 32 + q * 8];
#pragma unroll
                for (int k = 0; k < 4; k++) {
                    ar = mfma16(af[k], wOr[kh * 4 + k], ar);
                    az = mfma16(af[k], wOz[kh * 4 + k], az);
                }
            }
#pragma unroll
            for (int i = 0; i < 4; i++)
                rh_bf[q * 4 + i][colbase] = f2bf(sigmoidf_(ar[i]) * hreg[i]);
            wg_sync();  // rh ready

            f32x4 uu = Z4;
#pragma unroll
            for (int cc = 0; cc < 4; cc++) {  // chunk cc: kf pair {2cc, 2cc+1}
                bf16x8 au0 = *(const bf16x8*)&rh_bf[tc][(cc * 2) * 32 + q * 8];
                bf16x8 au1 = *(const bf16x8*)&rh_bf[tc][(cc * 2 + 1) * 32 + q * 8];
                ring_wait<4>();
                const ushort* sb = &ring[w][slot][0] + lo8;
                bf16x8 v0 = *(const bf16x8*)(sb);
                bf16x8 v1 = *(const bf16x8*)(sb + 512);
                slot = (slot == 2) ? 0 : slot + 1;
                pump();
                uu = mfma16(au0, v0, uu);
                uu = mfma16(au1, v1, uu);
            }
#pragma unroll
            for (int i = 0; i < 4; i++) {
                float zv = sigmoidf_(az[i]);
                float hv = hreg[i];
                float hn = hv + 0.25f * (1.f - zv) * (tanhf_(uu[i]) - hv);
                hreg[i] = hn;
                h_bf[q * 4 + i][colbase] = f2bf(hn);
            }
            wg_sync();  // h ready
        }

        // ---- GRU h-part: Whh, 12 chunks (kf-major across gates) ----
        f32x4 accr = Z4, accz = Z4, accn = Z4;
#define GRU_CHUNK(J, WN)                                                       \
        {                                                                      \
            constexpr int g_ = (J) % 3, kc_ = (J) / 3;                         \
            bf16x8 ah0 = *(const bf16x8*)&h_bf[tc][(kc_ * 2) * 32 + q * 8];    \
            bf16x8 ah1 = *(const bf16x8*)&h_bf[tc][(kc_ * 2 + 1) * 32 + q * 8];\
            ring_wait<WN>();                                                   \
            const ushort* sb = &ring[w][slot][0] + lo8;                        \
            bf16x8 v0 = *(const bf16x8*)(sb);                                  \
            bf16x8 v1 = *(const bf16x8*)(sb + 512);                            \
            slot = (slot == 2) ? 0 : slot + 1;                                 \
            pump();                                                            \
            f32x4* tg = (g_ == 0) ? &accr : (g_ == 1) ? &accz : &accn;         \
            *tg = mfma16(ah0, v0, *tg);                                        \
            *tg = mfma16(ah1, v1, *tg);                                        \
        }
        GRU_CHUNK(0, 4)  GRU_CHUNK(1, 4)  GRU_CHUNK(2, 4)  GRU_CHUNK(3, 4)
        GRU_CHUNK(4, 4)  GRU_CHUNK(5, 4)  GRU_CHUNK(6, 4)  GRU_CHUNK(7, 4)
        GRU_CHUNK(8, 4)  GRU_CHUNK(9, 4)  GRU_CHUNK(10, 2) GRU_CHUNK(11, 0)
#undef GRU_CHUNK
        wg_sync();  // all h_bf reads done

        // ---- GRU epilogue (xg regs drained long ago) ----
        {
            uint2 ur = xg[0], uz = xg[1], un = xg[2];
#pragma unroll
            for (int i = 0; i < 4; i++) {
                int sh = (i & 1) * 16;
                uint wr = (i < 2) ? ur.x : ur.y, wz = (i < 2) ? uz.x : uz.y,
                     wn = (i < 2) ? un.x : un.y;
                float xr = bf2f((ushort)(wr >> sh)), xz = bf2f((ushort)(wz >> sh)),
                      xn = bf2f((ushort)(wn >> sh));
                float rg = sigmoidf_(accr[i] + xr + rbv);
                float zg = sigmoidf_(accz[i] + xz + zbv);
                float ng = tanhf_(xn + rg * (accn[i] + hnbv));
                float hv = hreg[i];
                float hn = (1.f - zg) * ng + zg * hv;
                hreg[i] = hn;
                h_bf[q * 4 + i][colbase] = f2bf(hn);
            }
        }
        wg_sync();  // h_new visible

        // ---- coalesced h store (1 vmem store/thread; first op of next
        //      step's ledger) ----
        {
            int row = tid >> 6, col = (tid & 63) * 4;
            *(uint2*)&hseq[((size_t)(m0 + row) * 128 + t) * 256 + col] =
                *(const uint2*)&h_bf[row][col];
        }
    }
}

// ---------------------------------------------------------------------------
// Launch.  Workspace 129.6 MB:
//   [0, 100663296)            Xg swizzled [32][128][768][16] bf16
//   [100663296, 134217728)    X2 [65536,256] bf16  (aliased by hseq after use)
//   [134217728, ...)          packed weights (1.44 MB)
// ---------------------------------------------------------------------------
extern "C" void kernel_launch(void* const* d_in, const int* in_sizes, int n_in,
                              void* d_out, int out_size, void* d_ws, size_t ws_size,
                              hipStream_t stream) {
    const float* H   = (const float*)d_in[0];
    const float* W1  = (const float*)d_in[2];
    const float* b1  = (const float*)d_in[3];
    const float* W2  = (const float*)d_in[4];
    const float* b2  = (const float*)d_in[5];
    const float* Ohr = (const float*)d_in[6];
    const float* Ohz = (const float*)d_in[7];
    const float* Ohh = (const float*)d_in[8];
    const float* Wih = (const float*)d_in[9];
    const float* Whh = (const float*)d_in[10];
    const float* bih = (const float*)d_in[11];
    const float* bhh = (const float*)d_in[12];
    const float* Wr  = (const float*)d_in[13];
    const float* br  = (const float*)d_in[14];
    float* out = (float*)d_out;
    char* ws = (char*)d_ws;

    ushort* Xg   = (ushort*)(ws);
    ushort* X2   = (ushort*)(ws + 100663296);
    ushort* hseq = X2;  // alias: X2 dead before scan writes hseq
    char* pk = ws + 134217728;
    ushort* W1P  = (ushort*)(pk);
    ushort* W2P  = (ushort*)(pk + 131072);
    ushort* WrP  = (ushort*)(pk + 393216);
    ushort* OhrP = (ushort*)(pk + 458752);
    ushort* OhzP = (ushort*)(pk + 589824);
    ushort* OhhP = (ushort*)(pk + 720896);
    ushort* WihP = (ushort*)(pk + 851968);
    // end at +1245184

    pack_trans_k<<<dim3(32),  256, 0, stream>>>(W1,  W1P, 512, 128);
    pack_trans_k<<<dim3(64),  256, 0, stream>>>(W2,  W2P, 256, 512);
    pack_trans_k<<<dim3(16),  256, 0, stream>>>(Wr,  WrP, 128, 256);
    pack_direct_k<<<dim3(32), 256, 0, stream>>>(Ohr, OhrP, 256, 256);
    pack_direct_k<<<dim3(32), 256, 0, stream>>>(Ohz, OhzP, 256, 256);
    pack_direct_k<<<dim3(32), 256, 0, stream>>>(Ohh, OhhP, 256, 256);
    pack_direct_k<<<dim3(96), 256, 0, stream>>>(Wih, WihP, 768, 256);
    pack_direct_k<<<dim3(96), 256, 0, stream>>>(Whh, (ushort*)(pk + 1245184), 768, 256);
    ushort* WhhP = (ushort*)(pk + 1245184);

    // Phase A: X2 = MLP(H); Xg = X2 @ Wih^T + bih (swizzled for the scan)
    mlp_kernel<<<dim3(1024), 256, 0, stream>>>(H, W1P, b1, W2P, b2, X2);
    gemm128P<<<dim3(6, 512), 256, 0, stream>>>(X2, WihP, bih, Xg, 65536, 768, 256, 2);

    // Phase B: sequential scan -> hseq (32 WGs x 16 rows, 16 waves each)
    scan_fused<<<dim3(32), 1024, 0, stream>>>(Xg, OhrP, OhzP, OhhP, WhhP, bhh, hseq);

    // Phase C: out = hseq @ Wr + br (fp32)
    gemm128P<<<dim3(1, 512), 256, 0, stream>>>(hseq, WrP, br, out, 65536, 128, 256, 1);
}

// Round 6
// 2519.681 us; speedup vs baseline: 2.2208x; 1.1003x over previous
//
#include <hip/hip_runtime.h>

typedef unsigned short ushort;
typedef unsigned int uint;
typedef __bf16 bf16x8 __attribute__((ext_vector_type(8)));
typedef ushort ushort8 __attribute__((ext_vector_type(8)));
typedef float f32x4 __attribute__((ext_vector_type(4)));

#define Z4 f32x4{0.f, 0.f, 0.f, 0.f}

__device__ __forceinline__ f32x4 mfma16(bf16x8 a, bf16x8 b, f32x4 c) {
    return __builtin_amdgcn_mfma_f32_16x16x32_bf16(a, b, c, 0, 0, 0);
}
__device__ __forceinline__ float bf2f(ushort h) {
    union { uint u; float f; } v; v.u = ((uint)h) << 16; return v.f;
}
__device__ __forceinline__ ushort f2bf(float f) {  // RNE
    union { float f; uint u; } v; v.f = f;
    uint u = v.u;
    uint r = (u + 0x7fffu + ((u >> 16) & 1u)) >> 16;
    return (ushort)r;
}
__device__ __forceinline__ float sigmoidf_(float x) { return 1.f / (1.f + __expf(-x)); }
__device__ __forceinline__ float tanhf_(float x) {
    float e = __expf(2.f * x);
    return 1.f - 2.f / (e + 1.f);
}

typedef __attribute__((address_space(1))) uint guint;
typedef __attribute__((address_space(3))) uint luint;
__device__ __forceinline__ void dma16(const ushort* g, ushort* l) {
    __builtin_amdgcn_global_load_lds((const guint*)g, (luint*)l, 16, 0, 0);
}
template <int N> __device__ __forceinline__ void ring_wait() {
    asm volatile("s_waitcnt vmcnt(%0)" ::"n"(N) : "memory");
}
// raw barrier: LDS ordering only — does NOT drain the per-wave DMA ring (vmcnt)
__device__ __forceinline__ void wg_sync() {
    asm volatile("s_waitcnt lgkmcnt(0)\n\ts_barrier" ::: "memory");
}

// ---------------------------------------------------------------------------
// Weight pre-pack, MFMA-B fragment-major: frag F = ntile*(K/32)+kf, 1 KB each.
// ---------------------------------------------------------------------------
__global__ void pack_direct_k(const float* __restrict__ src, ushort* __restrict__ dst,
                              int N, int K) {  // src row-major [N,K]
    int total = (N >> 4) * (K >> 5) * 64;
    int idx = blockIdx.x * 256 + threadIdx.x;
    if (idx >= total) return;
    int l = idx & 63, f = idx >> 6;
    int kfrags = K >> 5;
    int nt = f / kfrags, kf = f - nt * kfrags;
    int n = nt * 16 + (l & 15);
    int k0 = kf * 32 + (l >> 4) * 8;
    const float* s = src + (size_t)n * K + k0;
    ushort8 u;
#pragma unroll
    for (int j = 0; j < 8; j++) u[j] = f2bf(s[j]);
    *(ushort8*)&dst[(size_t)f * 512 + l * 8] = u;
}
__global__ void pack_trans_k(const float* __restrict__ src, ushort* __restrict__ dst,
                             int N, int K) {  // src row-major [K,N]
    int total = (N >> 4) * (K >> 5) * 64;
    int idx = blockIdx.x * 256 + threadIdx.x;
    if (idx >= total) return;
    int l = idx & 63, f = idx >> 6;
    int kfrags = K >> 5;
    int nt = f / kfrags, kf = f - nt * kfrags;
    int n = nt * 16 + (l & 15);
    int k0 = kf * 32 + (l >> 4) * 8;
    ushort8 u;
#pragma unroll
    for (int j = 0; j < 8; j++) u[j] = f2bf(src[(size_t)(k0 + j) * N + n]);
    *(ushort8*)&dst[(size_t)f * 512 + l * 8] = u;
}

// ---------------------------------------------------------------------------
// Fused MLP: X2 = relu(H@W1+b1)@W2+b2  -> bf16 [65536,256]
// ---------------------------------------------------------------------------
__global__ __launch_bounds__(256) void mlp_kernel(
    const float* __restrict__ H,     // [65536,128] fp32
    const ushort* __restrict__ W1P,  // packed N=512,K=128
    const float* __restrict__ b1,
    const ushort* __restrict__ W2P,  // packed N=256,K=512
    const float* __restrict__ b2,
    ushort* __restrict__ X2)         // [65536,256] bf16
{
    __shared__ __align__(16) ushort sH[64][136];
    __shared__ __align__(16) ushort sT[64][264];
    __shared__ float sb1[512], sb2[256];
    const int tid = threadIdx.x;
    const int w = tid >> 6, lane = tid & 63;
    const int q = lane >> 4, tc = lane & 15;
    const int lo8 = lane * 8;
    const int m0 = blockIdx.x * 64;

    {   // stage H 64x128 fp32 -> bf16
        int r = tid >> 2, c0 = (tid & 3) * 32;
        const float* src = H + (size_t)(m0 + r) * 128 + c0;
#pragma unroll
        for (int v = 0; v < 4; v++) {
            float4 a = *(const float4*)(src + v * 8);
            float4 b = *(const float4*)(src + v * 8 + 4);
            ushort8 u;
            u[0] = f2bf(a.x); u[1] = f2bf(a.y); u[2] = f2bf(a.z); u[3] = f2bf(a.w);
            u[4] = f2bf(b.x); u[5] = f2bf(b.y); u[6] = f2bf(b.z); u[7] = f2bf(b.w);
            *(ushort8*)&sH[r][c0 + v * 8] = u;
        }
    }
    for (int i = tid; i < 512; i += 256) sb1[i] = b1[i];
    if (tid < 256) sb2[tid] = b2[tid];
    __syncthreads();

    bf16x8 af[4];
#pragma unroll
    for (int kb = 0; kb < 4; kb++) af[kb] = *(const bf16x8*)&sH[w * 16 + tc][kb * 32 + q * 8];

    f32x4 accH[16];
#pragma unroll
    for (int nt = 0; nt < 16; nt++) accH[nt] = Z4;

#pragma unroll 1
    for (int half = 0; half < 2; half++) {
        __syncthreads();  // protect sT reuse across halves
#pragma unroll
        for (int j = 0; j < 16; j++) {
            int n = half * 256 + j * 16 + tc;
            const ushort* bp = W1P + (size_t)((half * 16 + j) * 4) * 512 + lo8;
            f32x4 a = Z4;
#pragma unroll
            for (int kb = 0; kb < 4; kb++)
                a = mfma16(af[kb], *(const bf16x8*)(bp + kb * 512), a);
            float bv = sb1[n];
#pragma unroll
            for (int i = 0; i < 4; i++)
                sT[w * 16 + q * 4 + i][j * 16 + tc] = f2bf(fmaxf(a[i] + bv, 0.f));
        }
        __syncthreads();

        bf16x8 a2[8];
#pragma unroll
        for (int kb = 0; kb < 8; kb++) a2[kb] = *(const bf16x8*)&sT[w * 16 + tc][kb * 32 + q * 8];
#pragma unroll
        for (int nt = 0; nt < 16; nt++) {
            const ushort* bp = W2P + (size_t)(nt * 16 + half * 8) * 512 + lo8;
#pragma unroll
            for (int kb = 0; kb < 8; kb++)
                accH[nt] = mfma16(a2[kb], *(const bf16x8*)(bp + kb * 512), accH[nt]);
        }
    }

#pragma unroll
    for (int nt = 0; nt < 16; nt++) {
        int col = nt * 16 + tc;
        float bv = sb2[col];
#pragma unroll
        for (int i = 0; i < 4; i++)
            X2[(size_t)(m0 + w * 16 + q * 4 + i) * 256 + col] = f2bf(accH[nt][i] + bv);
    }
}

// ---------------------------------------------------------------------------
// GEMM, packed-B: C = A @ B^T + bias.  A bf16 row-major [M,K], BP packed.
// mode 0: bf16 row-major out; 1: fp32 row-major out; 2: bf16 Xg-swizzle out
// ---------------------------------------------------------------------------
__global__ __launch_bounds__(256) void gemm128P(
    const ushort* __restrict__ A, const ushort* __restrict__ BP,
    const float* __restrict__ bias, void* __restrict__ Cout,
    int M, int N, int K, int mode)
{
    __shared__ __align__(16) ushort sA[128][40];
    const int tid = threadIdx.x;
    const int lane = tid & 63, wid = tid >> 6;
    const int q = lane >> 4, tc = lane & 15;
    const int lo8 = lane * 8;
    const int wm = (wid >> 1) * 64, wn = (wid & 1) * 64;
    const int bm = blockIdx.y * 128, bn = blockIdx.x * 128;

    f32x4 acc[4][4];
#pragma unroll
    for (int im = 0; im < 4; im++)
#pragma unroll
        for (int in_ = 0; in_ < 4; in_++) acc[im][in_] = Z4;

    const int arow = tid >> 1, acol = (tid & 1) * 16;
    const int kfrags = K >> 5;

    for (int kc = 0; kc < K; kc += 32) {
        const ushort* ga = A + (size_t)(bm + arow) * K + kc + acol;
        ushort8 va0 = *(const ushort8*)ga;
        ushort8 va1 = *(const ushort8*)(ga + 8);
        __syncthreads();
        *(ushort8*)&sA[arow][acol] = va0;
        *(ushort8*)&sA[arow][acol + 8] = va1;
        __syncthreads();

        bf16x8 af[4], bf[4];
#pragma unroll
        for (int im = 0; im < 4; im++) af[im] = *(const bf16x8*)&sA[wm + im * 16 + tc][q * 8];
#pragma unroll
        for (int in_ = 0; in_ < 4; in_++) {
            int nt = ((bn + wn) >> 4) + in_;
            bf[in_] = *(const bf16x8*)(BP + (size_t)(nt * kfrags + (kc >> 5)) * 512 + lo8);
        }
#pragma unroll
        for (int im = 0; im < 4; im++)
#pragma unroll
            for (int in_ = 0; in_ < 4; in_++)
                acc[im][in_] = mfma16(af[im], bf[in_], acc[im][in_]);
    }

#pragma unroll
    for (int in_ = 0; in_ < 4; in_++) {
        int col = bn + wn + in_ * 16 + tc;
        float bv = bias[col];
#pragma unroll
        for (int im = 0; im < 4; im++) {
            int row0 = bm + wm + im * 16 + q * 4;
#pragma unroll
            for (int r = 0; r < 4; r++) {
                float v = acc[im][in_][r] + bv;
                int row = row0 + r;
                if (mode == 0) {
                    ((ushort*)Cout)[(size_t)row * N + col] = f2bf(v);
                } else if (mode == 1) {
                    ((float*)Cout)[(size_t)row * N + col] = v;
                } else {
                    int b = row >> 7, t = row & 127;
                    size_t dst = (((size_t)(b >> 4) * 128 + t) * N + col) * 16 + (b & 15);
                    ((ushort*)Cout)[dst] = f2bf(v);
                }
            }
        }
    }
}

// ---------------------------------------------------------------------------
// Sequential scan, v6: 64 WGs x 8 rows, 16 waves, LANE-REBALANCED epilogues.
// Round-5 evidence: per-CU elementwise VALU (~57% busy on active CUs) is the
// clock; per-wave splitting doesn't change it.  So: halve per-CU rows (8/WG,
// 64 CUs).  M=8 pads MFMA rows 8-15 with zeros; valid C-frag elements live
// only in lanes q<2, so after each MFMA we REDISTRIBUTE: lane>=32 takes
// elements {2,3} of lane-32 via __shfl(v, lane&31); every lane then processes
// exactly 2 elements (rows R,R+1; R = 4*(q&1)+2*(q>>1), col = w*16+tc).
// All transcendental/f2bf/update/xg work runs at 2 elem/thread (was 4) ->
// per-CU elementwise VALU halves.  MFMA/ring/pump per-CU unchanged.
// h_bf/rh_bf rows 8-15 zero-init, never written (A-frag padding reads 0).
// Per-element arithmetic order identical to v5 -> bit-identical output.
// vmcnt ledger identical to v5: store(1) | xg(3) | pump x3 (6), then 1 pump
// per chunk read; first wait<4> drains store+xg+chunk0; tail <2>,<0>.
// ---------------------------------------------------------------------------
__global__ __launch_bounds__(1024) void scan_fused(
    const ushort* __restrict__ XgSw,  // [32][128][768][16] bf16 swizzled
    const ushort* __restrict__ OhrP, const ushort* __restrict__ OhzP,
    const ushort* __restrict__ OhhP,  // packed N=256,K=256
    const ushort* __restrict__ WhhP,  // packed N=768,K=256
    const float*  __restrict__ bhh,   // [768]
    ushort* __restrict__ hseq)        // [65536,256] bf16, row = b*128+t
{
    const int bx = blockIdx.x;        // 64 WGs x 8 rows
    const int m0 = bx * 8;
    const int tid = threadIdx.x;
    const int w = tid >> 6, lane = tid & 63;   // 16 waves
    const int q = lane >> 4, tc = lane & 15;
    const int lo8 = lane * 8;
    const int colbase = w * 16 + tc;           // this wave's ntile = w
    const int R = ((lane >> 4) & 1) * 4 + ((lane >> 5) << 1);  // balanced row
    const bool lo = (q < 2);

    __shared__ __align__(16) ushort ring[16][3][1024];  // 96 KB (2 KB/slot)
    __shared__ __align__(16) ushort h_bf[16][264];      // 8.25 KB
    __shared__ __align__(16) ushort rh_bf[16][264];     // 8.25 KB

    for (int i = tid; i < 16 * 264; i += 1024) (&h_bf[0][0])[i] = 0;
    for (int i = tid; i < 16 * 264; i += 1024) (&rh_bf[0][0])[i] = 0;

    // per-thread biases (1 ntile -> scalars; same for both balanced rows)
    float rbv = bhh[colbase], zbv = bhh[256 + colbase], hnbv = bhh[512 + colbase];

    // persistent ODE r/z weights, this wave's ntile: 16 frags = 64 regs
    bf16x8 wOr[8], wOz[8];
#pragma unroll
    for (int f = 0; f < 8; f++) {
        wOr[f] = *(const bf16x8*)(OhrP + (size_t)(w * 8 + f) * 512 + lo8);
        wOz[f] = *(const bf16x8*)(OhzP + (size_t)(w * 8 + f) * 512 + lo8);
    }

    float hreg[2] = {0.f, 0.f};  // balanced rows R, R+1

    int ic = 0, islot = 0, slot = 0;
    auto pump = [&]() {
        if (ic >= 28) return;
        asm volatile("s_waitcnt lgkmcnt(0)" ::: "memory");  // slot-reuse fence
        const ushort* g;
        if (ic < 16) {
            g = OhhP + (size_t)(w * 8 + (ic & 3) * 2) * 512;
        } else {
            int j = ic - 16, gg = j % 3, kc = j / 3;
            g = WhhP + (size_t)((gg * 16 + w) * 8 + kc * 2) * 512;
        }
        g += lo8;
        ushort* sb = &ring[w][islot][0];
        dma16(g, sb); dma16(g + 512, sb + 512);
        ic++; islot = (islot == 2) ? 0 : islot + 1;
    };

    __syncthreads();  // zero-fill visible (no DMA yet)

#pragma unroll 1
    for (int t = 0; t < 128; t++) {
        // x-gates: 2 balanced rows per thread -> 3 x uint (rows R, R+1)
        const ushort* xgp = XgSw + (((size_t)(bx >> 1) * 128 + t) * 768) * 16
                            + (bx & 1) * 8 + R;
        uint xg[3];
#pragma unroll
        for (int g = 0; g < 3; g++)
            xg[g] = *(const uint*)(xgp + (size_t)(g * 256 + colbase) * 16);

        ic = 0; islot = 0; slot = 0;
        pump(); pump(); pump();

        // ---- 4 Euler ODE substeps ----
#pragma unroll 1
        for (int s = 0; s < 4; s++) {
            f32x4 ar = Z4, az = Z4;
#pragma unroll
            for (int kh = 0; kh < 2; kh++) {
                bf16x8 af[4];
#pragma unroll
                for (int k = 0; k < 4; k++)
                    af[k] = *(const bf16x8*)&h_bf[tc][(kh * 4 + k) * 32 + q * 8];
#pragma unroll
                for (int k = 0; k < 4; k++) {
                    ar = mfma16(af[k], wOr[kh * 4 + k], ar);
                    az = mfma16(af[k], wOz[kh * 4 + k], az);
                }
            }
            // rebalance ar/az: lane>=32 takes elems {2,3} of lane-32
            float ar2 = __shfl(ar[2], lane & 31), ar3 = __shfl(ar[3], lane & 31);
            float az2 = __shfl(az[2], lane & 31), az3 = __shfl(az[3], lane & 31);
            float ea0 = lo ? ar[0] : ar2, ea1 = lo ? ar[1] : ar3;
            float ez0 = lo ? az[0] : az2, ez1 = lo ? az[1] : az3;
            rh_bf[R + 0][colbase] = f2bf(sigmoidf_(ea0) * hreg[0]);
            rh_bf[R + 1][colbase] = f2bf(sigmoidf_(ea1) * hreg[1]);
            wg_sync();  // rh ready

            f32x4 uu = Z4;
#pragma unroll
            for (int cc = 0; cc < 4; cc++) {  // chunk cc: kf pair {2cc, 2cc+1}
                bf16x8 au0 = *(const bf16x8*)&rh_bf[tc][(cc * 2) * 32 + q * 8];
                bf16x8 au1 = *(const bf16x8*)&rh_bf[tc][(cc * 2 + 1) * 32 + q * 8];
                ring_wait<4>();
                const ushort* sb = &ring[w][slot][0] + lo8;
                bf16x8 v0 = *(const bf16x8*)(sb);
                bf16x8 v1 = *(const bf16x8*)(sb + 512);
                slot = (slot == 2) ? 0 : slot + 1;
                pump();
                uu = mfma16(au0, v0, uu);
                uu = mfma16(au1, v1, uu);
            }
            // rebalance uu; z already balanced (ez0/ez1)
            float uu2 = __shfl(uu[2], lane & 31), uu3 = __shfl(uu[3], lane & 31);
            float eu0 = lo ? uu[0] : uu2, eu1 = lo ? uu[1] : uu3;
            {
                float zv = sigmoidf_(ez0), hv = hreg[0];
                float hn = hv + 0.25f * (1.f - zv) * (tanhf_(eu0) - hv);
                hreg[0] = hn;
                h_bf[R + 0][colbase] = f2bf(hn);
            }
            {
                float zv = sigmoidf_(ez1), hv = hreg[1];
                float hn = hv + 0.25f * (1.f - zv) * (tanhf_(eu1) - hv);
                hreg[1] = hn;
                h_bf[R + 1][colbase] = f2bf(hn);
            }
            wg_sync();  // h ready
        }

        // ---- GRU h-part: Whh, 12 chunks (kf-major across gates) ----
        f32x4 accr = Z4, accz = Z4, accn = Z4;
#define GRU_CHUNK(J, WN)                                                       \
        {                                                                      \
            constexpr int g_ = (J) % 3, kc_ = (J) / 3;                         \
            bf16x8 ah0 = *(const bf16x8*)&h_bf[tc][(kc_ * 2) * 32 + q * 8];    \
            bf16x8 ah1 = *(const bf16x8*)&h_bf[tc][(kc_ * 2 + 1) * 32 + q * 8];\
            ring_wait<WN>();                                                   \
            const ushort* sb = &ring[w][slot][0] + lo8;                        \
            bf16x8 v0 = *(const bf16x8*)(sb);                                  \
            bf16x8 v1 = *(const bf16x8*)(sb + 512);                            \
            slot = (slot == 2) ? 0 : slot + 1;                                 \
            pump();                                                            \
            f32x4* tg = (g_ == 0) ? &accr : (g_ == 1) ? &accz : &accn;         \
            *tg = mfma16(ah0, v0, *tg);                                        \
            *tg = mfma16(ah1, v1, *tg);                                        \
        }
        GRU_CHUNK(0, 4)  GRU_CHUNK(1, 4)  GRU_CHUNK(2, 4)  GRU_CHUNK(3, 4)
        GRU_CHUNK(4, 4)  GRU_CHUNK(5, 4)  GRU_CHUNK(6, 4)  GRU_CHUNK(7, 4)
        GRU_CHUNK(8, 4)  GRU_CHUNK(9, 4)  GRU_CHUNK(10, 2) GRU_CHUNK(11, 0)
#undef GRU_CHUNK
        wg_sync();  // all h_bf reads done

        // ---- GRU epilogue, balanced (2 elems/thread) ----
        {
            float r2 = __shfl(accr[2], lane & 31), r3 = __shfl(accr[3], lane & 31);
            float z2 = __shfl(accz[2], lane & 31), z3 = __shfl(accz[3], lane & 31);
            float n2 = __shfl(accn[2], lane & 31), n3 = __shfl(accn[3], lane & 31);
            float er0 = lo ? accr[0] : r2, er1 = lo ? accr[1] : r3;
            float ez0 = lo ? accz[0] : z2, ez1 = lo ? accz[1] : z3;
            float en0 = lo ? accn[0] : n2, en1 = lo ? accn[1] : n3;
            {
                float xr = bf2f((ushort)(xg[0])), xz = bf2f((ushort)(xg[1])),
                      xn = bf2f((ushort)(xg[2]));
                float rg = sigmoidf_(er0 + xr + rbv);
                float zg = sigmoidf_(ez0 + xz + zbv);
                float ng = tanhf_(xn + rg * (en0 + hnbv));
                float hv = hreg[0];
                float hn = (1.f - zg) * ng + zg * hv;
                hreg[0] = hn;
                h_bf[R + 0][colbase] = f2bf(hn);
            }
            {
                float xr = bf2f((ushort)(xg[0] >> 16)), xz = bf2f((ushort)(xg[1] >> 16)),
                      xn = bf2f((ushort)(xg[2] >> 16));
                float rg = sigmoidf_(er1 + xr + rbv);
                float zg = sigmoidf_(ez1 + xz + zbv);
                float ng = tanhf_(xn + rg * (en1 + hnbv));
                float hv = hreg[1];
                float hn = (1.f - zg) * ng + zg * hv;
                hreg[1] = hn;
                h_bf[R + 1][colbase] = f2bf(hn);
            }
        }
        wg_sync();  // h_new visible

        // ---- coalesced h store: 8 rows x 256 cols, 1 uint per thread ----
        {
            int row = tid >> 7, col = (tid & 127) * 2;
            *(uint*)&hseq[((size_t)(m0 + row) * 128 + t) * 256 + col] =
                *(const uint*)&h_bf[row][col];
        }
    }
}

// ---------------------------------------------------------------------------
// Launch.  Workspace 129.6 MB:
//   [0, 100663296)            Xg swizzled [32][128][768][16] bf16
//   [100663296, 134217728)    X2 [65536,256] bf16  (aliased by hseq after use)
//   [134217728, ...)          packed weights (1.44 MB)
// ---------------------------------------------------------------------------
extern "C" void kernel_launch(void* const* d_in, const int* in_sizes, int n_in,
                              void* d_out, int out_size, void* d_ws, size_t ws_size,
                              hipStream_t stream) {
    const float* H   = (const float*)d_in[0];
    const float* W1  = (const float*)d_in[2];
    const float* b1  = (const float*)d_in[3];
    const float* W2  = (const float*)d_in[4];
    const float* b2  = (const float*)d_in[5];
    const float* Ohr = (const float*)d_in[6];
    const float* Ohz = (const float*)d_in[7];
    const float* Ohh = (const float*)d_in[8];
    const float* Wih = (const float*)d_in[9];
    const float* Whh = (const float*)d_in[10];
    const float* bih = (const float*)d_in[11];
    const float* bhh = (const float*)d_in[12];
    const float* Wr  = (const float*)d_in[13];
    const float* br  = (const float*)d_in[14];
    float* out = (float*)d_out;
    char* ws = (char*)d_ws;

    ushort* Xg   = (ushort*)(ws);
    ushort* X2   = (ushort*)(ws + 100663296);
    ushort* hseq = X2;  // alias: X2 dead before scan writes hseq
    char* pk = ws + 134217728;
    ushort* W1P  = (ushort*)(pk);
    ushort* W2P  = (ushort*)(pk + 131072);
    ushort* WrP  = (ushort*)(pk + 393216);
    ushort* OhrP = (ushort*)(pk + 458752);
    ushort* OhzP = (ushort*)(pk + 589824);
    ushort* OhhP = (ushort*)(pk + 720896);
    ushort* WihP = (ushort*)(pk + 851968);
    // end at +1245184

    pack_trans_k<<<dim3(32),  256, 0, stream>>>(W1,  W1P, 512, 128);
    pack_trans_k<<<dim3(64),  256, 0, stream>>>(W2,  W2P, 256, 512);
    pack_trans_k<<<dim3(16),  256, 0, stream>>>(Wr,  WrP, 128, 256);
    pack_direct_k<<<dim3(32), 256, 0, stream>>>(Ohr, OhrP, 256, 256);
    pack_direct_k<<<dim3(32), 256, 0, stream>>>(Ohz, OhzP, 256, 256);
    pack_direct_k<<<dim3(32), 256, 0, stream>>>(Ohh, OhhP, 256, 256);
    pack_direct_k<<<dim3(96), 256, 0, stream>>>(Wih, WihP, 768, 256);
    pack_direct_k<<<dim3(96), 256, 0, stream>>>(Whh, (ushort*)(pk + 1245184), 768, 256);
    ushort* WhhP = (ushort*)(pk + 1245184);

    // Phase A: X2 = MLP(H); Xg = X2 @ Wih^T + bih (swizzled for the scan)
    mlp_kernel<<<dim3(1024), 256, 0, stream>>>(H, W1P, b1, W2P, b2, X2);
    gemm128P<<<dim3(6, 512), 256, 0, stream>>>(X2, WihP, bih, Xg, 65536, 768, 256, 2);

    // Phase B: sequential scan -> hseq (64 WGs x 8 rows, 16 waves each)
    scan_fused<<<dim3(64), 1024, 0, stream>>>(Xg, OhrP, OhzP, OhhP, WhhP, bhh, hseq);

    // Phase C: out = hseq @ Wr + br (fp32)
    gemm128P<<<dim3(1, 512), 256, 0, stream>>>(hseq, WrP, br, out, 65536, 128, 256, 1);
}